// Round 7
// baseline (18858.434 us; speedup 1.0000x reference)
//
#include <hip/hip_runtime.h>

namespace {

constexpr int kNU = 100000;
constexpr int kNI = 50000;
constexpr int kN  = 150000;
constexpr int kH  = 128;
constexpr int kEP = 2000000;
constexpr int kEN = 1000000;
constexpr int kL  = 2;

constexpr int SCAN_BS = 256;
constexpr int SCAN_IT = 4;
constexpr int SCAN_TILE = SCAN_BS * SCAN_IT;

constexpr int kAP = 66;  // padded A row stride in LDS (2-way bank alias = free)

// ---- degree counting ----
__global__ void count_kernel(const int* __restrict__ dst, int E, int* __restrict__ deg) {
  int t = blockIdx.x * blockDim.x + threadIdx.x;
  if (t < E) atomicAdd(&deg[dst[t]], 1);
}

__global__ void inv_kernel(const int* __restrict__ deg, float* __restrict__ inv, int n) {
  int t = blockIdx.x * blockDim.x + threadIdx.x;
  if (t < n) inv[t] = 1.0f / fmaxf((float)deg[t], 1.0f);
}

// ---- 3-phase exclusive scan ----
__global__ void scan_partial(const int* __restrict__ deg, int n,
                             int* __restrict__ off, int* __restrict__ sums) {
  __shared__ int sh[SCAN_BS];
  const int t = threadIdx.x;
  const int base = blockIdx.x * SCAN_TILE;
  int v[SCAN_IT];
  int run = 0;
#pragma unroll
  for (int j = 0; j < SCAN_IT; ++j) {
    int idx = base + t * SCAN_IT + j;
    v[j] = (idx < n) ? deg[idx] : 0;
    run += v[j];
  }
  sh[t] = run;
  __syncthreads();
  for (int d = 1; d < SCAN_BS; d <<= 1) {
    int x = (t >= d) ? sh[t - d] : 0;
    __syncthreads();
    sh[t] += x;
    __syncthreads();
  }
  int acc = sh[t] - run;
  if (t == SCAN_BS - 1) sums[blockIdx.x] = sh[t];
#pragma unroll
  for (int j = 0; j < SCAN_IT; ++j) {
    int idx = base + t * SCAN_IT + j;
    acc += v[j];
    if (idx < n) off[idx + 1] = acc;
  }
}

__global__ void scan_sums(int* __restrict__ sums, int nb) {
  __shared__ int sh[SCAN_BS];
  const int t = threadIdx.x;
  int v = (t < nb) ? sums[t] : 0;
  sh[t] = v;
  __syncthreads();
  for (int d = 1; d < SCAN_BS; d <<= 1) {
    int x = (t >= d) ? sh[t - d] : 0;
    __syncthreads();
    sh[t] += x;
    __syncthreads();
  }
  if (t < nb) sums[t] = sh[t] - v;
}

__global__ void scan_add(int* __restrict__ off, int n, const int* __restrict__ sums) {
  int t = blockIdx.x * blockDim.x + threadIdx.x;
  if (t == 0) off[0] = 0;
  if (t < n) off[t + 1] += sums[t / SCAN_TILE];
}

// ---- CSR fill ----
__global__ void fill_kernel(const int* __restrict__ src, const int* __restrict__ dst, int E,
                            int* __restrict__ cursor, int* __restrict__ eids) {
  int t = blockIdx.x * blockDim.x + threadIdx.x;
  if (t < E) {
    int p = atomicAdd(&cursor[dst[t]], 1);
    eids[p] = src[t];
  }
}

// ---- CSR gather-mean (full 128-wide) ----
template <bool SPLIT>
__global__ __launch_bounds__(256) void agg_csr(
    const int* __restrict__ off, const int* __restrict__ eids,
    const float* __restrict__ inv,
    const float* __restrict__ zu, const float* __restrict__ zi,
    float* __restrict__ aggOut) {
  const int g = threadIdx.x >> 5;
  const int lane = threadIdx.x & 31;
  const int row = blockIdx.x * 8 + g;
  if (row >= kN) return;
  const int s = off[row], e = off[row + 1];
  float4 acc = make_float4(0.f, 0.f, 0.f, 0.f);
  int i = s;
  for (; i + 2 <= e; i += 2) {
    int s0 = eids[i], s1 = eids[i + 1];
    const float* r0;
    const float* r1;
    if (SPLIT) {
      r0 = (s0 < kNU) ? zu + (size_t)s0 * kH : zi + (size_t)(s0 - kNU) * kH;
      r1 = (s1 < kNU) ? zu + (size_t)s1 * kH : zi + (size_t)(s1 - kNU) * kH;
    } else {
      r0 = zu + (size_t)s0 * kH;
      r1 = zu + (size_t)s1 * kH;
    }
    float4 v0 = *reinterpret_cast<const float4*>(r0 + lane * 4);
    float4 v1 = *reinterpret_cast<const float4*>(r1 + lane * 4);
    acc.x += v0.x + v1.x; acc.y += v0.y + v1.y;
    acc.z += v0.z + v1.z; acc.w += v0.w + v1.w;
  }
  if (i < e) {
    int s0 = eids[i];
    const float* r0;
    if (SPLIT) r0 = (s0 < kNU) ? zu + (size_t)s0 * kH : zi + (size_t)(s0 - kNU) * kH;
    else r0 = zu + (size_t)s0 * kH;
    float4 v0 = *reinterpret_cast<const float4*>(r0 + lane * 4);
    acc.x += v0.x; acc.y += v0.y; acc.z += v0.z; acc.w += v0.w;
  }
  const float sc = inv[row];
  float4 r = make_float4(acc.x * sc, acc.y * sc, acc.z * sc, acc.w * sc);
  *reinterpret_cast<float4*>(aggOut + (size_t)row * kH + lane * 4) = r;
}

// ---- fused GEMM half-layer, async-staged A + global-streamed W ----
// out[:, ooff:+64] = relu( P1[:, o1:+64] @ W1[0:64,:] + P2[:, o2:+64] @ W1[64:128,:]
//                          + X[:, oz:+(NCHUNK-2)*64] @ W2 + bias )
// Block: 128 rows x 64 cols; 256 threads; thread = 8 rows x 4 cols.
// Per 64-wide K chunk: next chunk's A panel is prefetched to REGISTERS before
// compute (HBM latency hides under ~4096 cyc of FMA), then ds_write after the
// barrier (T14 async-STAGE split). W is read per-lane from global (L1-hot,
// 4 b128 per 128 FMA). LDS = A only (33KB) -> 4 blocks/CU.
// In-place safe: all X global reads are prefetches issued before any out write;
// each block touches only its own rows.
template <int NCHUNK, bool SPLITX>
__global__ __launch_bounds__(256, 4) void gemm2(
    const float* __restrict__ P1, int o1,
    const float* __restrict__ P2, int o2,
    const float* __restrict__ W1,   // 128 x 64
    const float* __restrict__ Xu, const float* __restrict__ Xi, int oz,
    const float* __restrict__ W2,   // (NCHUNK-2)*64 x 64
    const float* __restrict__ bias,
    float* __restrict__ out, int ooff) {
  __shared__ float at[128 * kAP];  // 33792 B
  const int tid = threadIdx.x;
  const int rb0 = blockIdx.x * 128;
  const int c4 = (tid & 15) << 2;  // col offset (staging & compute)
  const int srow = tid >> 4;       // staging row base
  const int r0 = (tid >> 4) << 3;  // compute row base

  float4 pf[8];

  auto src_row = [&](int c, int rr) -> const float* {
    if (c == 0) return P1 + (size_t)rr * kH + o1;
    if (c == 1) return P2 + (size_t)rr * kH + o2;
    int xo = oz + (c - 2) * 64;
    if (SPLITX)
      return ((rr < kNU) ? Xu + (size_t)rr * kH : Xi + (size_t)(rr - kNU) * kH) + xo;
    return Xu + (size_t)rr * kH + xo;
  };

  auto prefetch = [&](int c) {
#pragma unroll
    for (int it = 0; it < 8; ++it) {
      int rr = rb0 + srow + 16 * it;
      if (rr >= kN) rr = kN - 1;
      pf[it] = *reinterpret_cast<const float4*>(src_row(c, rr) + c4);
    }
  };
  auto dswrite = [&]() {
#pragma unroll
    for (int it = 0; it < 8; ++it)
      *reinterpret_cast<float4*>(&at[(srow + 16 * it) * kAP + c4]) = pf[it];
  };

  float4 acc[8];
  {
    float4 b4 = *reinterpret_cast<const float4*>(bias + c4);
#pragma unroll
    for (int r = 0; r < 8; ++r) acc[r] = b4;
  }

  // prologue: stage chunk 0
  prefetch(0);
  dswrite();
  __syncthreads();

#pragma unroll
  for (int c = 0; c < NCHUNK; ++c) {
    if (c + 1 < NCHUNK) prefetch(c + 1);  // in flight under compute
    const float* W = (c < 2) ? (W1 + c * 64 * 64) : (W2 + (c - 2) * 64 * 64);
#pragma unroll
    for (int kc = 0; kc < 64; kc += 4) {
      float4 wv[4];
#pragma unroll
      for (int j = 0; j < 4; ++j)
        wv[j] = *reinterpret_cast<const float4*>(W + (kc + j) * 64 + c4);
      float4 av[8];
#pragma unroll
      for (int r = 0; r < 8; ++r)
        av[r] = *reinterpret_cast<const float4*>(at + (r0 + r) * kAP + kc);
#pragma unroll
      for (int r = 0; r < 8; ++r) {
        float4 a = av[r];
        acc[r].x = fmaf(a.w, wv[3].x, fmaf(a.z, wv[2].x, fmaf(a.y, wv[1].x, fmaf(a.x, wv[0].x, acc[r].x))));
        acc[r].y = fmaf(a.w, wv[3].y, fmaf(a.z, wv[2].y, fmaf(a.y, wv[1].y, fmaf(a.x, wv[0].y, acc[r].y))));
        acc[r].z = fmaf(a.w, wv[3].z, fmaf(a.z, wv[2].z, fmaf(a.y, wv[1].z, fmaf(a.x, wv[0].z, acc[r].z))));
        acc[r].w = fmaf(a.w, wv[3].w, fmaf(a.z, wv[2].w, fmaf(a.y, wv[1].w, fmaf(a.x, wv[0].w, acc[r].w))));
      }
    }
    if (c + 1 < NCHUNK) {
      __syncthreads();  // all waves done reading at[] for chunk c
      dswrite();        // cheap: loads long since landed; ~8 ds_write_b128
      __syncthreads();  // writes visible
    }
  }

  // all global X reads were issued before any write -> in-place safe
#pragma unroll
  for (int r = 0; r < 8; ++r) {
    int rr = rb0 + r0 + r;
    if (rr < kN) {
      float4 v = acc[r];
      v.x = fmaxf(v.x, 0.0f); v.y = fmaxf(v.y, 0.0f);
      v.z = fmaxf(v.z, 0.0f); v.w = fmaxf(v.w, 0.0f);
      *reinterpret_cast<float4*>(out + (size_t)rr * kH + ooff + c4) = v;
    }
  }
}

inline float* align16(void* p) {
  return (float*)(((uintptr_t)p + 15) & ~(uintptr_t)15);
}

}  // namespace

extern "C" void kernel_launch(void* const* d_in, const int* in_sizes, int n_in,
                              void* d_out, int out_size, void* d_ws, size_t ws_size,
                              hipStream_t stream) {
  const int*   pos     = (const int*)d_in[0];
  const int*   neg     = (const int*)d_in[1];
  const float* users   = (const float*)d_in[2];
  const float* items   = (const float*)d_in[3];
  const float* c1_wpl  = (const float*)d_in[4];
  const float* c1_wpr  = (const float*)d_in[5];
  const float* c1_bpr  = (const float*)d_in[6];
  const float* c1_wnl  = (const float*)d_in[7];
  const float* c1_wnr  = (const float*)d_in[8];
  const float* c1_bnr  = (const float*)d_in[9];
  const float* cw_pl   = (const float*)d_in[10];
  const float* cw_pr   = (const float*)d_in[11];
  const float* cb_pr   = (const float*)d_in[12];
  const float* cw_nl   = (const float*)d_in[13];
  const float* cw_nr   = (const float*)d_in[14];
  const float* cb_nr   = (const float*)d_in[15];
  float* out = (float*)d_out;

  const int* pos_src = pos;
  const int* pos_dst = pos + kEP;
  const int* neg_src = neg;
  const int* neg_dst = neg + kEN;

  // ---- workspace layout ----
  float* invp = (float*)d_ws;
  float* invn = invp + kN;
  int* degp   = (int*)(invn + kN);
  int* degn   = degp + kN;
  int* offp   = degn + kN;
  int* offn   = offp + kN + 1;
  int* sums   = offn + kN + 1;
  int* eidp   = sums + 256;
  int* eidn   = eidp + kEP;
  float* aggP = align16(eidn + kEN);
  float* aggN = aggP + (size_t)kN * kH;
  const size_t need = (size_t)((char*)(aggN + (size_t)kN * kH) - (char*)d_ws);
  if (ws_size < need) return;

  const int nbP = (kN + SCAN_TILE - 1) / SCAN_TILE;

  // ---- degree counts + inverses ----
  hipMemsetAsync(degp, 0, (size_t)2 * kN * sizeof(int), stream);
  count_kernel<<<(kEP + 255) / 256, 256, 0, stream>>>(pos_dst, kEP, degp);
  count_kernel<<<(kEN + 255) / 256, 256, 0, stream>>>(neg_dst, kEN, degn);
  inv_kernel<<<(kN + 255) / 256, 256, 0, stream>>>(degp, invp, kN);
  inv_kernel<<<(kN + 255) / 256, 256, 0, stream>>>(degn, invn, kN);

  // ---- CSR build (pos) ----
  scan_partial<<<nbP, SCAN_BS, 0, stream>>>(degp, kN, offp, sums);
  scan_sums<<<1, SCAN_BS, 0, stream>>>(sums, nbP);
  scan_add<<<(kN + 255) / 256, 256, 0, stream>>>(offp, kN, sums);
  hipMemcpyAsync(degp, offp, (size_t)kN * sizeof(int), hipMemcpyDeviceToDevice, stream);
  fill_kernel<<<(kEP + 255) / 256, 256, 0, stream>>>(pos_src, pos_dst, kEP, degp, eidp);

  // ---- CSR build (neg) ----
  scan_partial<<<nbP, SCAN_BS, 0, stream>>>(degn, kN, offn, sums);
  scan_sums<<<1, SCAN_BS, 0, stream>>>(sums, nbP);
  scan_add<<<(kN + 255) / 256, 256, 0, stream>>>(offn, kN, sums);
  hipMemcpyAsync(degn, offn, (size_t)kN * sizeof(int), hipMemcpyDeviceToDevice, stream);
  fill_kernel<<<(kEN + 255) / 256, 256, 0, stream>>>(neg_src, neg_dst, kEN, degn, eidn);

  const int gA = (kN + 7) / 8;
  const int gG = (kN + 127) / 128;

  // ---- layer 1 ----
  agg_csr<true><<<gA, 256, 0, stream>>>(offp, eidp, invp, users, items, aggP);
  agg_csr<true><<<gA, 256, 0, stream>>>(offn, eidn, invn, users, items, aggN);
  gemm2<4, true><<<gG, 256, 0, stream>>>(aggP, 0, aggP, 64, c1_wpl,
                                         users, items, 0, c1_wpr, c1_bpr, out, 0);
  gemm2<4, true><<<gG, 256, 0, stream>>>(aggN, 0, aggN, 64, c1_wnl,
                                         users, items, 0, c1_wnr, c1_bnr, out, 64);

  // ---- inner layers: z lives in d_out, updated in place ----
  for (int l = 0; l < kL; ++l) {
    const float* wpl = cw_pl + (size_t)l * kH * 64;
    const float* wpr = cw_pr + (size_t)l * 64 * 64;
    const float* bpr = cb_pr + (size_t)l * 64;
    const float* wnl = cw_nl + (size_t)l * kH * 64;
    const float* wnr = cw_nr + (size_t)l * 64 * 64;
    const float* bnr = cb_nr + (size_t)l * 64;

    // aggP = mean_p(z) = [a_pp | a_np]; aggN = mean_n(z) = [a_pn | a_nn]
    agg_csr<false><<<gA, 256, 0, stream>>>(offp, eidp, invp, out, nullptr, aggP);
    agg_csr<false><<<gA, 256, 0, stream>>>(offn, eidn, invn, out, nullptr, aggN);

    // out_pos = relu(concat(a_pp, a_nn) @ wpl + zp @ wpr + bpr)
    gemm2<3, false><<<gG, 256, 0, stream>>>(aggP, 0, aggN, 64, wpl,
                                            out, nullptr, 0, wpr, bpr, out, 0);
    // out_neg = relu(concat(a_np, a_pn) @ wnl + zn @ wnr + bnr)
    gemm2<3, false><<<gG, 256, 0, stream>>>(aggP, 64, aggN, 0, wnl,
                                            out, nullptr, 64, wnr, bnr, out, 64);
  }
}

// Round 8
// 1479.208 us; speedup vs baseline: 12.7490x; 12.7490x over previous
//
#include <hip/hip_runtime.h>

namespace {

constexpr int kNU = 100000;
constexpr int kNI = 50000;
constexpr int kN  = 150000;
constexpr int kH  = 128;
constexpr int kEP = 2000000;
constexpr int kEN = 1000000;
constexpr int kL  = 2;

constexpr int SCAN_BS = 256;
constexpr int SCAN_IT = 4;
constexpr int SCAN_TILE = SCAN_BS * SCAN_IT;

// HBM -> LDS direct DMA, 16B per lane. LDS dest is wave-uniform base + lane*16.
__device__ __forceinline__ void load16_to_lds(const float* g, float* l) {
  __builtin_amdgcn_global_load_lds(
      (const __attribute__((address_space(1))) unsigned int*)g,
      (__attribute__((address_space(3))) unsigned int*)l, 16, 0, 0);
}

// ---- degree counting ----
__global__ void count_kernel(const int* __restrict__ dst, int E, int* __restrict__ deg) {
  int t = blockIdx.x * blockDim.x + threadIdx.x;
  if (t < E) atomicAdd(&deg[dst[t]], 1);
}

__global__ void inv_kernel(const int* __restrict__ deg, float* __restrict__ inv, int n) {
  int t = blockIdx.x * blockDim.x + threadIdx.x;
  if (t < n) inv[t] = 1.0f / fmaxf((float)deg[t], 1.0f);
}

// ---- 3-phase exclusive scan ----
__global__ void scan_partial(const int* __restrict__ deg, int n,
                             int* __restrict__ off, int* __restrict__ sums) {
  __shared__ int sh[SCAN_BS];
  const int t = threadIdx.x;
  const int base = blockIdx.x * SCAN_TILE;
  int v[SCAN_IT];
  int run = 0;
#pragma unroll
  for (int j = 0; j < SCAN_IT; ++j) {
    int idx = base + t * SCAN_IT + j;
    v[j] = (idx < n) ? deg[idx] : 0;
    run += v[j];
  }
  sh[t] = run;
  __syncthreads();
  for (int d = 1; d < SCAN_BS; d <<= 1) {
    int x = (t >= d) ? sh[t - d] : 0;
    __syncthreads();
    sh[t] += x;
    __syncthreads();
  }
  int acc = sh[t] - run;
  if (t == SCAN_BS - 1) sums[blockIdx.x] = sh[t];
#pragma unroll
  for (int j = 0; j < SCAN_IT; ++j) {
    int idx = base + t * SCAN_IT + j;
    acc += v[j];
    if (idx < n) off[idx + 1] = acc;
  }
}

__global__ void scan_sums(int* __restrict__ sums, int nb) {
  __shared__ int sh[SCAN_BS];
  const int t = threadIdx.x;
  int v = (t < nb) ? sums[t] : 0;
  sh[t] = v;
  __syncthreads();
  for (int d = 1; d < SCAN_BS; d <<= 1) {
    int x = (t >= d) ? sh[t - d] : 0;
    __syncthreads();
    sh[t] += x;
    __syncthreads();
  }
  if (t < nb) sums[t] = sh[t] - v;
}

__global__ void scan_add(int* __restrict__ off, int n, const int* __restrict__ sums) {
  int t = blockIdx.x * blockDim.x + threadIdx.x;
  if (t == 0) off[0] = 0;
  if (t < n) off[t + 1] += sums[t / SCAN_TILE];
}

// ---- CSR fill ----
__global__ void fill_kernel(const int* __restrict__ src, const int* __restrict__ dst, int E,
                            int* __restrict__ cursor, int* __restrict__ eids) {
  int t = blockIdx.x * blockDim.x + threadIdx.x;
  if (t < E) {
    int p = atomicAdd(&cursor[dst[t]], 1);
    eids[p] = src[t];
  }
}

// ---- CSR gather-mean (full 128-wide) ----
template <bool SPLIT>
__global__ __launch_bounds__(256) void agg_csr(
    const int* __restrict__ off, const int* __restrict__ eids,
    const float* __restrict__ inv,
    const float* __restrict__ zu, const float* __restrict__ zi,
    float* __restrict__ aggOut) {
  const int g = threadIdx.x >> 5;
  const int lane = threadIdx.x & 31;
  const int row = blockIdx.x * 8 + g;
  if (row >= kN) return;
  const int s = off[row], e = off[row + 1];
  float4 acc = make_float4(0.f, 0.f, 0.f, 0.f);
  int i = s;
  for (; i + 2 <= e; i += 2) {
    int s0 = eids[i], s1 = eids[i + 1];
    const float* r0;
    const float* r1;
    if (SPLIT) {
      r0 = (s0 < kNU) ? zu + (size_t)s0 * kH : zi + (size_t)(s0 - kNU) * kH;
      r1 = (s1 < kNU) ? zu + (size_t)s1 * kH : zi + (size_t)(s1 - kNU) * kH;
    } else {
      r0 = zu + (size_t)s0 * kH;
      r1 = zu + (size_t)s1 * kH;
    }
    float4 v0 = *reinterpret_cast<const float4*>(r0 + lane * 4);
    float4 v1 = *reinterpret_cast<const float4*>(r1 + lane * 4);
    acc.x += v0.x + v1.x; acc.y += v0.y + v1.y;
    acc.z += v0.z + v1.z; acc.w += v0.w + v1.w;
  }
  if (i < e) {
    int s0 = eids[i];
    const float* r0;
    if (SPLIT) r0 = (s0 < kNU) ? zu + (size_t)s0 * kH : zi + (size_t)(s0 - kNU) * kH;
    else r0 = zu + (size_t)s0 * kH;
    float4 v0 = *reinterpret_cast<const float4*>(r0 + lane * 4);
    acc.x += v0.x; acc.y += v0.y; acc.z += v0.z; acc.w += v0.w;
  }
  const float sc = inv[row];
  float4 r = make_float4(acc.x * sc, acc.y * sc, acc.z * sc, acc.w * sc);
  *reinterpret_cast<float4*>(aggOut + (size_t)row * kH + lane * 4) = r;
}

// ---- fused GEMM half-layer: global_load_lds double-buffered A, 2-D reg tiling ----
// out[:, ooff:+64] = relu( P1[:, o1:+64] @ W1[0:64,:] + P2[:, o2:+64] @ W1[64:128,:]
//                          + X[:, oz:+(NCHUNK-2)*64] @ W2 + bias )
// Block: 128 rows x 64 cols; 256 threads; thread = 8 rows x 4 cols.
// Per 64-wide K chunk: next chunk's A panel DMA'd HBM->LDS via global_load_lds
// (no VGPR cost) while current chunk computes; one __syncthreads per chunk.
// LDS [2][128][64] linear (DMA constraint); bank conflicts on A-reads removed by
// XOR-swizzling the SOURCE column (u ^= (row>>3)&3) and the read address alike.
// A-reads are 16-lane broadcast; W streamed per-lane from global (L1/L2-hot).
// In-place safe: all X reads are DMA'd to LDS before the final barrier; each
// block reads/writes only its own 128 rows.
template <int NCHUNK, bool SPLITX>
__global__ __launch_bounds__(256, 2) void gemm2(
    const float* __restrict__ P1, int o1,
    const float* __restrict__ P2, int o2,
    const float* __restrict__ W1,   // 128 x 64
    const float* __restrict__ Xu, const float* __restrict__ Xi, int oz,
    const float* __restrict__ W2,   // (NCHUNK-2)*64 x 64
    const float* __restrict__ bias,
    float* __restrict__ out, int ooff) {
  __shared__ float at[2][128 * 64];  // 64 KB
  const int tid = threadIdx.x;
  const int rb0 = blockIdx.x * 128;
  const int lane = tid & 63;
  const int wv = tid >> 6;
  const int c4 = (tid & 15) << 2;   // output col offset
  const int r0 = (tid >> 4) << 3;   // row base (8-aligned)
  const int sw = (tid >> 4) & 3;    // read-side swizzle = (row>>3)&3 for r0..r0+7

  auto src_row = [&](int c, int rr) -> const float* {
    if (c == 0) return P1 + (size_t)rr * kH + o1;
    if (c == 1) return P2 + (size_t)rr * kH + o2;
    int xo = oz + (c - 2) * 64;
    if (SPLITX)
      return ((rr < kNU) ? Xu + (size_t)rr * kH : Xi + (size_t)(rr - kNU) * kH) + xo;
    return Xu + (size_t)rr * kH + xo;
  };

  // DMA one 128x64 chunk into at[buf]; source col pre-swizzled so that
  // LDS[row][u] = global[row][u ^ ((row>>3)&3)].
  auto stage = [&](int c, int buf) {
    float* base = &at[buf][0];
#pragma unroll
    for (int j = 0; j < 8; ++j) {
      int blk = wv * 8 + j;                 // 1KB region index, wave-uniform
      int row = blk * 4 + (lane >> 4);      // this lane's row
      int rr = rb0 + row;
      if (rr >= kN) rr = kN - 1;
      int u = (lane & 15) ^ ((row >> 3) & 3);
      load16_to_lds(src_row(c, rr) + u * 4, base + blk * 256);
    }
  };

  float4 acc[8];
  {
    float4 b4 = *reinterpret_cast<const float4*>(bias + c4);
#pragma unroll
    for (int r = 0; r < 8; ++r) acc[r] = b4;
  }

  stage(0, 0);
  __syncthreads();  // prologue drain (paid once)

  int cur = 0;
  for (int c = 0; c < NCHUNK; ++c) {
    if (c + 1 < NCHUNK) stage(c + 1, cur ^ 1);  // async DMA under compute
    const float* W = (c < 2) ? (W1 + c * 64 * 64) : (W2 + (c - 2) * 64 * 64);
    const float* A = &at[cur][0];
#pragma unroll 2
    for (int kc = 0; kc < 64; kc += 4) {
      float4 wv4[4];
#pragma unroll
      for (int j = 0; j < 4; ++j)
        wv4[j] = *reinterpret_cast<const float4*>(W + (kc + j) * 64 + c4);
      const int uu = (((kc >> 2) ^ sw) << 2);
      float4 av[8];
#pragma unroll
      for (int r = 0; r < 8; ++r)
        av[r] = *reinterpret_cast<const float4*>(A + (r0 + r) * 64 + uu);
#pragma unroll
      for (int r = 0; r < 8; ++r) {
        float4 a = av[r];
        acc[r].x = fmaf(a.w, wv4[3].x, fmaf(a.z, wv4[2].x, fmaf(a.y, wv4[1].x, fmaf(a.x, wv4[0].x, acc[r].x))));
        acc[r].y = fmaf(a.w, wv4[3].y, fmaf(a.z, wv4[2].y, fmaf(a.y, wv4[1].y, fmaf(a.x, wv4[0].y, acc[r].y))));
        acc[r].z = fmaf(a.w, wv4[3].z, fmaf(a.z, wv4[2].z, fmaf(a.y, wv4[1].z, fmaf(a.x, wv4[0].z, acc[r].z))));
        acc[r].w = fmaf(a.w, wv4[3].w, fmaf(a.z, wv4[2].w, fmaf(a.y, wv4[1].w, fmaf(a.x, wv4[0].w, acc[r].w))));
      }
    }
    __syncthreads();  // vmcnt drained here: stage(c+1) landed under compute
    cur ^= 1;
  }

  // all X reads (DMA) completed before the final barrier -> in-place safe
#pragma unroll
  for (int r = 0; r < 8; ++r) {
    int rr = rb0 + r0 + r;
    if (rr < kN) {
      float4 v = acc[r];
      v.x = fmaxf(v.x, 0.0f); v.y = fmaxf(v.y, 0.0f);
      v.z = fmaxf(v.z, 0.0f); v.w = fmaxf(v.w, 0.0f);
      *reinterpret_cast<float4*>(out + (size_t)rr * kH + ooff + c4) = v;
    }
  }
}

inline float* align16(void* p) {
  return (float*)(((uintptr_t)p + 15) & ~(uintptr_t)15);
}

}  // namespace

extern "C" void kernel_launch(void* const* d_in, const int* in_sizes, int n_in,
                              void* d_out, int out_size, void* d_ws, size_t ws_size,
                              hipStream_t stream) {
  const int*   pos     = (const int*)d_in[0];
  const int*   neg     = (const int*)d_in[1];
  const float* users   = (const float*)d_in[2];
  const float* items   = (const float*)d_in[3];
  const float* c1_wpl  = (const float*)d_in[4];
  const float* c1_wpr  = (const float*)d_in[5];
  const float* c1_bpr  = (const float*)d_in[6];
  const float* c1_wnl  = (const float*)d_in[7];
  const float* c1_wnr  = (const float*)d_in[8];
  const float* c1_bnr  = (const float*)d_in[9];
  const float* cw_pl   = (const float*)d_in[10];
  const float* cw_pr   = (const float*)d_in[11];
  const float* cb_pr   = (const float*)d_in[12];
  const float* cw_nl   = (const float*)d_in[13];
  const float* cw_nr   = (const float*)d_in[14];
  const float* cb_nr   = (const float*)d_in[15];
  float* out = (float*)d_out;

  const int* pos_src = pos;
  const int* pos_dst = pos + kEP;
  const int* neg_src = neg;
  const int* neg_dst = neg + kEN;

  // ---- workspace layout ----
  float* invp = (float*)d_ws;
  float* invn = invp + kN;
  int* degp   = (int*)(invn + kN);
  int* degn   = degp + kN;
  int* offp   = degn + kN;
  int* offn   = offp + kN + 1;
  int* sums   = offn + kN + 1;
  int* eidp   = sums + 256;
  int* eidn   = eidp + kEP;
  float* aggP = align16(eidn + kEN);
  float* aggN = aggP + (size_t)kN * kH;
  const size_t need = (size_t)((char*)(aggN + (size_t)kN * kH) - (char*)d_ws);
  if (ws_size < need) return;

  const int nbP = (kN + SCAN_TILE - 1) / SCAN_TILE;

  // ---- degree counts + inverses ----
  hipMemsetAsync(degp, 0, (size_t)2 * kN * sizeof(int), stream);
  count_kernel<<<(kEP + 255) / 256, 256, 0, stream>>>(pos_dst, kEP, degp);
  count_kernel<<<(kEN + 255) / 256, 256, 0, stream>>>(neg_dst, kEN, degn);
  inv_kernel<<<(kN + 255) / 256, 256, 0, stream>>>(degp, invp, kN);
  inv_kernel<<<(kN + 255) / 256, 256, 0, stream>>>(degn, invn, kN);

  // ---- CSR build (pos) ----
  scan_partial<<<nbP, SCAN_BS, 0, stream>>>(degp, kN, offp, sums);
  scan_sums<<<1, SCAN_BS, 0, stream>>>(sums, nbP);
  scan_add<<<(kN + 255) / 256, 256, 0, stream>>>(offp, kN, sums);
  hipMemcpyAsync(degp, offp, (size_t)kN * sizeof(int), hipMemcpyDeviceToDevice, stream);
  fill_kernel<<<(kEP + 255) / 256, 256, 0, stream>>>(pos_src, pos_dst, kEP, degp, eidp);

  // ---- CSR build (neg) ----
  scan_partial<<<nbP, SCAN_BS, 0, stream>>>(degn, kN, offn, sums);
  scan_sums<<<1, SCAN_BS, 0, stream>>>(sums, nbP);
  scan_add<<<(kN + 255) / 256, 256, 0, stream>>>(offn, kN, sums);
  hipMemcpyAsync(degn, offn, (size_t)kN * sizeof(int), hipMemcpyDeviceToDevice, stream);
  fill_kernel<<<(kEN + 255) / 256, 256, 0, stream>>>(neg_src, neg_dst, kEN, degn, eidn);

  const int gA = (kN + 7) / 8;
  const int gG = (kN + 127) / 128;

  // ---- layer 1 ----
  agg_csr<true><<<gA, 256, 0, stream>>>(offp, eidp, invp, users, items, aggP);
  agg_csr<true><<<gA, 256, 0, stream>>>(offn, eidn, invn, users, items, aggN);
  gemm2<4, true><<<gG, 256, 0, stream>>>(aggP, 0, aggP, 64, c1_wpl,
                                         users, items, 0, c1_wpr, c1_bpr, out, 0);
  gemm2<4, true><<<gG, 256, 0, stream>>>(aggN, 0, aggN, 64, c1_wnl,
                                         users, items, 0, c1_wnr, c1_bnr, out, 64);

  // ---- inner layers: z lives in d_out, updated in place ----
  for (int l = 0; l < kL; ++l) {
    const float* wpl = cw_pl + (size_t)l * kH * 64;
    const float* wpr = cw_pr + (size_t)l * 64 * 64;
    const float* bpr = cb_pr + (size_t)l * 64;
    const float* wnl = cw_nl + (size_t)l * kH * 64;
    const float* wnr = cw_nr + (size_t)l * 64 * 64;
    const float* bnr = cb_nr + (size_t)l * 64;

    // aggP = mean_p(z) = [a_pp | a_np]; aggN = mean_n(z) = [a_pn | a_nn]
    agg_csr<false><<<gA, 256, 0, stream>>>(offp, eidp, invp, out, nullptr, aggP);
    agg_csr<false><<<gA, 256, 0, stream>>>(offn, eidn, invn, out, nullptr, aggN);

    // out_pos = relu(concat(a_pp, a_nn) @ wpl + zp @ wpr + bpr)
    gemm2<3, false><<<gG, 256, 0, stream>>>(aggP, 0, aggN, 64, wpl,
                                            out, nullptr, 0, wpr, bpr, out, 0);
    // out_neg = relu(concat(a_np, a_pn) @ wnl + zn @ wnr + bnr)
    gemm2<3, false><<<gG, 256, 0, stream>>>(aggP, 64, aggN, 0, wnl,
                                            out, nullptr, 64, wnr, bnr, out, 64);
  }
}